// Round 2
// baseline (114.358 us; speedup 1.0000x reference)
//
#include <hip/hip_runtime.h>
#include <stdint.h>

// Problem constants (fixed by setup_inputs): B=32, N=512, D=512
#define BATCH 32
#define NDIM 512
#define DDIM 512
#define XELEMS (BATCH * NDIM * DDIM)   // 8388608
#define WELEMS (DDIM * DDIM)           // 262144

typedef _Float16 f16x8 __attribute__((ext_vector_type(8)));
typedef _Float16 f16x4v __attribute__((ext_vector_type(4)));
typedef float f32x4 __attribute__((ext_vector_type(4)));

// --- async global -> LDS, 16 bytes per lane (global_load_lds_dwordx4) ---
__device__ __forceinline__ void gl_lds16(const _Float16* g, _Float16* l) {
    __builtin_amdgcn_global_load_lds(
        (const __attribute__((address_space(1))) unsigned int*)(g),
        (__attribute__((address_space(3))) unsigned int*)(l),
        16, 0, 0);
}

// ---------------- pass 0: X fp32->fp16 convert  +  W fp32->fp16 transpose ----------
// (unchanged from the 112.8 µs verified kernel)
__global__ __launch_bounds__(256) void prep(const float4* __restrict__ X4,
                                            f16x4v* __restrict__ Xh4,
                                            const float* __restrict__ W,
                                            _Float16* __restrict__ Wt) {
    __shared__ float tile[32][33];
    int bid = blockIdx.x;
    if (bid < XELEMS / 4 / 256) {
        int i = bid * 256 + threadIdx.x;
        float4 v = X4[i];
        f16x4v o;
        o.x = (_Float16)v.x;
        o.y = (_Float16)v.y;
        o.z = (_Float16)v.z;
        o.w = (_Float16)v.w;
        Xh4[i] = o;
    } else {
        int t = bid - XELEMS / 4 / 256;   // 0..255
        int bx = t & 15;                  // e-tile
        int by = t >> 4;                  // d-tile
        int tx = threadIdx.x & 31;
        int ty = threadIdx.x >> 5;        // 0..7
        for (int r = ty; r < 32; r += 8)
            tile[r][tx] = W[(by * 32 + r) * DDIM + bx * 32 + tx];
        __syncthreads();
        for (int r = ty; r < 32; r += 8)
            Wt[(size_t)(bx * 32 + r) * DDIM + by * 32 + tx] = (_Float16)tile[tx][r];
    }
}

// ---------------- fused: S_b = (X_b @ W) @ X_b^T + bias, diag = 0 -------------------
// [R1 this session — FUSION of the previous pass1+pass2. Rationale: 112.8 µs is ~10x
//  above all pipe floors; dominant costs must be inter-pass tails + Y round-trip +
//  unamortized 8-iter K-loop drains. A 64-row Y-slice (64x512 fp16 = 64 KB) fits in
//  LDS, so each block runs GEMM1 into LDS then GEMM2 out of it. All fragment/swizzle
//  algebra identical to the verified kernel (same gl_lds chunk scheme, same pa XOR,
//  same m89 C/D layout). LDS 136 KB -> 1 block/CU, 8 waves (2/SIMD).]
//
// Grid: 256 blocks = rs*32 + batch  (blk%8 = batch%8 -> a batch's 8 row-slice blocks
// share one XCD -> X_b (512 KB, read twice) is L2-resident; Wt resident everywhere).
__global__ __launch_bounds__(512) void fused(const _Float16* __restrict__ Xh,
                                             const _Float16* __restrict__ Wt,
                                             float* __restrict__ Sout,
                                             const float* __restrict__ bias_ptr) {
    __shared__ __align__(16) _Float16 Ylds[64 * 512];  // 64 KB — Y-slice, phase1 out / phase2 A
    __shared__ __align__(16) _Float16 As[8 * 512];     //  8 KB — 64x64 X-row tile (phase1 A)
    __shared__ __align__(16) _Float16 Bs[64 * 512];    // 64 KB — 512x64 tile (Wt / X_b rows)

    const int tid  = threadIdx.x;
    const int lane = tid & 63;
    const int wv   = tid >> 6;        // 0..7
    const int quad = lane >> 4;       // 0..3
    const int l16  = lane & 15;

    // staging lane decomposition: one wave-issue = one 8-row x 64-col fp16 chunk.
    // XOR swizzle: physical 16B slot lc holds logical k-chunk lc^lr  (rule-21 pair
    // with the pa XOR on the read side — identical to the verified kernel).
    const int lr = lane >> 3;         // row within chunk (0..7)
    const int lc = lane & 7;          // physical 16B slot
    const int lk = (lc ^ lr) * 8;     // logical fp16 col offset to fetch

    const int blk   = blockIdx.x;     // 256 blocks
    const int batch = blk & 31;
    const int r0    = (blk >> 5) * 64;  // row-slice [r0, r0+64)

    const _Float16* Xb = Xh + (size_t)batch * (NDIM * DDIM);

    f32x4 acc[4][4];
#pragma unroll
    for (int i = 0; i < 4; ++i)
#pragma unroll
        for (int j = 0; j < 4; ++j)
            acc[i][j] = (f32x4){0.f, 0.f, 0.f, 0.f};

    // ================= phase 1: Y = X_b[r0:r0+64][:] @ Wt^T  (K = d = 512) =========
    for (int it = 0; it < 8; ++it) {
        const int k0 = it * 64;
        // stage A: wave wv stages row-chunk wv  (rows r0 + wv*8 + lr)
        gl_lds16(Xb + (size_t)(r0 + wv * 8 + lr) * DDIM + k0 + lk, &As[wv * 512]);
        // stage B: Wt rows e = wv*64 + t*8 + lr  (full 512 e-rows across 8 waves)
#pragma unroll
        for (int t = 0; t < 8; ++t)
            gl_lds16(Wt + (size_t)(wv * 64 + t * 8 + lr) * DDIM + k0 + lk,
                     &Bs[(wv * 8 + t) * 512]);
        __syncthreads();

#pragma unroll
        for (int kkc = 0; kkc < 8; kkc += 4) {
            const int pa = (((kkc + quad) ^ (l16 & 7)) * 8);
            f16x8 a[4], b[4];
#pragma unroll
            for (int mt = 0; mt < 4; ++mt)
                a[mt] = *(const f16x8*)&As[(mt * 16 + l16) * 64 + pa];
#pragma unroll
            for (int nt = 0; nt < 4; ++nt)
                b[nt] = *(const f16x8*)&Bs[(wv * 64 + nt * 16 + l16) * 64 + pa];
#pragma unroll
            for (int mt = 0; mt < 4; ++mt)
#pragma unroll
                for (int nt = 0; nt < 4; ++nt)
                    acc[mt][nt] = __builtin_amdgcn_mfma_f32_16x16x32_f16(
                        a[mt], b[nt], acc[mt][nt], 0, 0, 0);
        }
        __syncthreads();
    }

    // ---- Y -> Ylds (fp16), e-chunk XOR-swizzled so phase2 A-reads reuse the pa XOR.
    // C/D layout: col = l16 (=e within wave strip), row = quad*4 + r  (m89-verified).
#pragma unroll
    for (int mt = 0; mt < 4; ++mt)
#pragma unroll
        for (int nt = 0; nt < 4; ++nt)
#pragma unroll
            for (int r = 0; r < 4; ++r) {
                int i = mt * 16 + quad * 4 + r;        // Y row (0..63)
                int e = wv * 64 + nt * 16 + l16;       // Y col (0..511)
                int c = e >> 3, j = e & 7;
                Ylds[i * 512 + (((c ^ (i & 7)) << 3) | j)] = (_Float16)acc[mt][nt][r];
            }
    __syncthreads();   // Ylds complete (cross-wave reads next); also frees Bs

    // ================= phase 2: S = Y @ X_b^T  (K = e = 512) =======================
#pragma unroll
    for (int i = 0; i < 4; ++i)
#pragma unroll
        for (int j = 0; j < 4; ++j)
            acc[i][j] = (f32x4){0.f, 0.f, 0.f, 0.f};

    for (int it = 0; it < 8; ++it) {
        const int e0 = it * 64;
        // stage B: X_b rows j = wv*64 + t*8 + lr, cols e0..e0+63
#pragma unroll
        for (int t = 0; t < 8; ++t)
            gl_lds16(Xb + (size_t)(wv * 64 + t * 8 + lr) * DDIM + e0 + lk,
                     &Bs[(wv * 8 + t) * 512]);
        __syncthreads();

#pragma unroll
        for (int kkc = 0; kkc < 8; kkc += 4) {
            const int pa = (((kkc + quad) ^ (l16 & 7)) * 8);
            const int cy = it * 8 + kkc + quad;            // global e-chunk (0..63)
            const int pay = ((cy ^ (l16 & 7)) * 8);        // Ylds swizzled offset
            f16x8 a[4], b[4];
#pragma unroll
            for (int mt = 0; mt < 4; ++mt)
                a[mt] = *(const f16x8*)&Ylds[(mt * 16 + l16) * 512 + pay];
#pragma unroll
            for (int nt = 0; nt < 4; ++nt)
                b[nt] = *(const f16x8*)&Bs[(wv * 64 + nt * 16 + l16) * 64 + pa];
#pragma unroll
            for (int mt = 0; mt < 4; ++mt)
#pragma unroll
                for (int nt = 0; nt < 4; ++nt)
                    acc[mt][nt] = __builtin_amdgcn_mfma_f32_16x16x32_f16(
                        a[mt], b[nt], acc[mt][nt], 0, 0, 0);
        }
        __syncthreads();
    }

    // ---- epilogue: bias, zero diagonal, fp32 store
    const float bias = bias_ptr[0];
#pragma unroll
    for (int mt = 0; mt < 4; ++mt)
#pragma unroll
        for (int nt = 0; nt < 4; ++nt)
#pragma unroll
            for (int r = 0; r < 4; ++r) {
                int gi = r0 + mt * 16 + quad * 4 + r;   // row within batch (0..511)
                int gj = wv * 64 + nt * 16 + l16;       // col within batch (0..511)
                float v = acc[mt][nt][r] + bias;
                if (gi == gj) v = 0.f;
                Sout[((size_t)batch * NDIM + gi) * NDIM + gj] = v;
            }
}

extern "C" void kernel_launch(void* const* d_in, const int* in_sizes, int n_in,
                              void* d_out, int out_size, void* d_ws, size_t ws_size,
                              hipStream_t stream) {
    const float* X  = (const float*)d_in[0];   // (32, 512, 512) fp32
    const float* W  = (const float*)d_in[1];   // (512, 512) fp32
    const float* bp = (const float*)d_in[2];   // scalar fp32
    float* out = (float*)d_out;                // (32, 512, 512) fp32

    // workspace layout (fp16): Xh[8388608] | Wt[262144]
    _Float16* Xh = (_Float16*)d_ws;
    _Float16* Wt = Xh + XELEMS;

    // pass 0: dtype conversion + W transpose
    prep<<<XELEMS / 4 / 256 + 256, 256, 0, stream>>>((const float4*)X, (f16x4v*)Xh, W, Wt);

    // fused: per (batch, 64-row slice): Y-slice = X_b W into LDS, then S = Y X_b^T
    fused<<<256, 512, 0, stream>>>(Xh, Wt, out, bp);

    (void)in_sizes; (void)n_in; (void)out_size; (void)ws_size;
}